// Round 7
// baseline (139.577 us; speedup 1.0000x reference)
//
#include <hip/hip_runtime.h>
#include <hip/hip_bf16.h>

typedef _Float16 f16;
typedef __attribute__((ext_vector_type(8))) _Float16 f16x8;
typedef __attribute__((ext_vector_type(4))) float f32x4;

#define IN 128
#define OUT 128
#define NB 8192

// ws layout (bytes)
#define WB_OFF   0ull
#define XH_OFF   4227072ull          // 129*128*128*2
#define BIAS_OFF 6324224ull          // + 8192*128*2
#define PARTS_OFF 6324736ull         // + 512

// ---- prep: WB f16 [129][o][j] (c<128: lc_w[o,pos(c,j)], diag 0; c=128: w1*scale),
// ---- xh f16 = (x - tr)/sc, bias[o] = sum_j tr[j]*w1[o,j]
__global__ __launch_bounds__(256) void prep_kernel(
    const float* __restrict__ x, const float* __restrict__ lcw, const float* __restrict__ w1,
    const float* __restrict__ sc, const float* __restrict__ tr,
    f16* __restrict__ WB, f16* __restrict__ xh, float* __restrict__ bias)
{
    const int bid = blockIdx.x;
    if (bid < 1032) {                          // WB: 129*16384 f16 elems
        size_t idx = (size_t)bid * 2048 + (size_t)threadIdx.x * 8;
        int c   = (int)(idx >> 14);
        int rem = (int)(idx & 16383);
        int o   = rem >> 7;
        int j0  = rem & 127;
        f16x8 v;
        if (c < 128) {
            const float* lr = lcw + (size_t)o * 16256 + (size_t)c * 127;
            #pragma unroll
            for (int e = 0; e < 8; ++e) {
                int j = j0 + e;
                float f = (j == c) ? 0.f : lr[(j < c) ? j : (j - 1)];
                v[e] = (f16)f;
            }
        } else {
            #pragma unroll
            for (int e = 0; e < 8; ++e) {
                int j = j0 + e;
                v[e] = (f16)(w1[o * 128 + j] * sc[j]);
            }
        }
        *(f16x8*)(WB + idx) = v;
    } else if (bid < 1544) {                   // xh
        size_t idx = (size_t)(bid - 1032) * 2048 + (size_t)threadIdx.x * 8;
        int j0 = (int)(idx & 127);
        const float4 x0 = *(const float4*)(x + idx);
        const float4 x1 = *(const float4*)(x + idx + 4);
        const float4 s0 = *(const float4*)(sc + j0);
        const float4 s1 = *(const float4*)(sc + j0 + 4);
        const float4 t0 = *(const float4*)(tr + j0);
        const float4 t1 = *(const float4*)(tr + j0 + 4);
        f16x8 v;
        v[0] = (f16)((x0.x - t0.x) / s0.x); v[1] = (f16)((x0.y - t0.y) / s0.y);
        v[2] = (f16)((x0.z - t0.z) / s0.z); v[3] = (f16)((x0.w - t0.w) / s0.w);
        v[4] = (f16)((x1.x - t1.x) / s1.x); v[5] = (f16)((x1.y - t1.y) / s1.y);
        v[6] = (f16)((x1.z - t1.z) / s1.z); v[7] = (f16)((x1.w - t1.w) / s1.w);
        *(f16x8*)(xh + idx) = v;
    } else {                                   // bias
        const int lane = threadIdx.x & 63;
        const int wv   = threadIdx.x >> 6;
        const float2 t2 = *(const float2*)(tr + lane * 2);
        for (int o = wv; o < 128; o += 4) {
            const float2 w2 = *(const float2*)(w1 + o * 128 + lane * 2);
            float s = t2.x * w2.x + t2.y * w2.y;
            #pragma unroll
            for (int m = 1; m < 64; m <<= 1) s += __shfl_xor(s, m);
            if (lane == 0) bias[o] = s;
        }
    }
}

// ---- main: 64*KSPLIT WGs, 512 thr = 8 waves (2M x 4N). KSPLIT=8 -> 512 WGs = 2 blocks/CU.
// In-reg A (asm keep-alive), LDS B double-buffer via global_load_lds (pre-swizzled src),
// counted-vmcnt 2-deep pipeline with raw s_barrier (never vmcnt(0) mid-loop).
template<int KSPLIT>
__global__ __launch_bounds__(512, 1) void lc_gemm(
    const f16* __restrict__ xh, const f16* __restrict__ WB, float* __restrict__ parts)
{
    constexpr int CPK = 128 / KSPLIT;
    __shared__ f16 Bb[2][16384];               // 2 x 32 KB
    __shared__ f16 xls[(CPK + 1) * 128];       // per-block x column slice

    const int tid = threadIdx.x;
    const int bid = blockIdx.x;
    const int mt  = bid / KSPLIT;
    const int kq  = bid % KSPLIT;              // == XCD id for KSPLIT=8
    const int row0 = mt << 7;

    const int lane = tid & 63;
    const int wv   = tid >> 6;
    const int wm   = wv >> 2;                  // 0..1 : 64-row half
    const int wn   = wv & 3;                   // 0..3 : 32-col group
    const int cl   = lane & 15;
    const int kg   = lane >> 4;

    const int c_lo = (kq == 0) ? 0 : (1 + kq * CPK);

    // ---- A-base fragments, resident whole kernel
    f16x8 ab[4][4];
    #pragma unroll
    for (int rb = 0; rb < 4; ++rb) {
        const size_t rw = (size_t)(row0 + wm * 64 + rb * 16 + cl) * IN;
        #pragma unroll
        for (int s = 0; s < 4; ++s)
            ab[rb][s] = *(const f16x8*)(xh + rw + s * 32 + kg * 8);
    }
    #pragma unroll
    for (int rb = 0; rb < 4; ++rb)
        #pragma unroll
        for (int s = 0; s < 4; ++s)
            asm volatile("" : "+v"(ab[rb][s]));      // pin: no remat/sink

    // ---- DMA source offsets (pre-swizzled: bits4-7 ^= o&15) + LDS read offsets
    int dmac[4];
    #pragma unroll
    for (int p = 0; p < 4; ++p) {
        int L = ((p * 8 + wv) << 10) | (lane << 4);
        dmac[p] = L ^ (((L >> 8) & 15) << 4);
    }
    int boff[2][4];
    #pragma unroll
    for (int cb = 0; cb < 2; ++cb)
        #pragma unroll
        for (int s = 0; s < 4; ++s) {
            int o = wn * 32 + cb * 16 + cl;
            boff[cb][s] = (o << 8) + ((((s << 2) + kg) ^ (o & 15)) << 4);
        }

    auto stageB = [&](int c, int buf) {
        const char* src = (const char*)WB + ((size_t)c << 15);
        #pragma unroll
        for (int p = 0; p < 4; ++p) {
            __builtin_amdgcn_global_load_lds(
                (const __attribute__((address_space(1))) unsigned int*)(src + dmac[p]),
                (__attribute__((address_space(3))) unsigned int*)((char*)(&Bb[buf][0]) + ((p * 8 + wv) << 10)),
                16, 0, 0);
        }
    };

    f32x4 acc[4][2];
    #pragma unroll
    for (int rb = 0; rb < 4; ++rb)
        #pragma unroll
        for (int cb = 0; cb < 2; ++cb)
            acc[rb][cb] = (f32x4){0.f, 0.f, 0.f, 0.f};

#define KLOOP(NCV)                                                              \
    {                                                                           \
        constexpr int NC = NCV;                                                 \
        for (int pass = 0; pass < (NC + 3) / 4; ++pass) {                       \
            int cp = pass * 4 + (tid >> 7);                                     \
            if (cp < NC) {                                                      \
                int c = c_lo + cp;                                              \
                f16 v = (c < 128)                                               \
                    ? xh[(size_t)(row0 + (tid & 127)) * IN + c]                 \
                    : (f16)1.0f;                                                \
                xls[cp * 128 + (tid & 127)] = v;                                \
            }                                                                   \
        }                                                                       \
        stageB(c_lo + 0, 0);                                                    \
        stageB(c_lo + 1, 1);                                                    \
        __syncthreads();                                                        \
        _Pragma("unroll")                                                       \
        for (int ci = 0; ci < NC; ++ci) {                                       \
            if (ci >= 2) {                                                      \
                if (ci + 1 < NC) asm volatile("s_waitcnt vmcnt(4)" ::: "memory");\
                else             asm volatile("s_waitcnt vmcnt(0)" ::: "memory");\
                __builtin_amdgcn_s_barrier();                                   \
                __builtin_amdgcn_sched_barrier(0);                              \
            }                                                                   \
            const char* bbase = (const char*)(&Bb[ci & 1][0]);                  \
            f16x8 bf[2][4];                                                     \
            _Pragma("unroll")                                                   \
            for (int cb = 0; cb < 2; ++cb)                                      \
                _Pragma("unroll")                                               \
                for (int s = 0; s < 4; ++s)                                     \
                    bf[cb][s] = *(const f16x8*)(bbase + boff[cb][s]);           \
            f16 xs[4];                                                          \
            _Pragma("unroll")                                                   \
            for (int rb = 0; rb < 4; ++rb)                                      \
                xs[rb] = xls[ci * 128 + wm * 64 + rb * 16 + cl];                \
            _Pragma("unroll")                                                   \
            for (int s = 0; s < 4; ++s)                                         \
                _Pragma("unroll")                                               \
                for (int rb = 0; rb < 4; ++rb) {                                \
                    f16x8 xbv;                                                  \
                    _Pragma("unroll")                                           \
                    for (int e = 0; e < 8; ++e) xbv[e] = xs[rb];                \
                    f16x8 af = ab[rb][s] * xbv;                                 \
                    _Pragma("unroll")                                           \
                    for (int cb = 0; cb < 2; ++cb)                              \
                        acc[rb][cb] = __builtin_amdgcn_mfma_f32_16x16x32_f16(   \
                            af, bf[cb][s], acc[rb][cb], 0, 0, 0);               \
                }                                                               \
            __builtin_amdgcn_sched_barrier(0);                                  \
            __builtin_amdgcn_s_barrier();                                       \
            __builtin_amdgcn_sched_barrier(0);                                  \
            if (ci + 2 < NC) stageB(c_lo + ci + 2, ci & 1);                     \
        }                                                                       \
    }

    if (kq == 0) KLOOP(CPK + 1) else KLOOP(CPK)
#undef KLOOP

    float* po = parts + (size_t)kq * ((size_t)NB * OUT);
    #pragma unroll
    for (int rb = 0; rb < 4; ++rb) {
        const int grow = row0 + wm * 64 + rb * 16 + kg * 4;
        #pragma unroll
        for (int cb = 0; cb < 2; ++cb) {
            const int col = wn * 32 + cb * 16 + cl;
            #pragma unroll
            for (int q = 0; q < 4; ++q)
                po[(size_t)(grow + q) * OUT + col] = acc[rb][cb][q];
        }
    }
}

// ---- reduce split-K partials + bias, then LayerNorm. 32 lanes per row (float4/lane).
template<int KSPLIT>
__global__ __launch_bounds__(256) void reduce_ln(
    const float* __restrict__ parts, const float* __restrict__ bias,
    const float* __restrict__ gamma, const float* __restrict__ beta,
    float* __restrict__ out)
{
    const int lane = threadIdx.x & 63;
    const int l5   = lane & 31;
    const int row  = blockIdx.x * 8 + (threadIdx.x >> 6) * 2 + (lane >> 5);
    const int c0   = l5 * 4;
    const size_t off = (size_t)row * OUT + c0;
    const size_t Q = (size_t)NB * OUT;

    float4 bb = *(const float4*)(bias + c0);
    float4 y = bb;
    #pragma unroll
    for (int k = 0; k < KSPLIT; ++k) {
        float4 p = *(const float4*)(parts + (size_t)k * Q + off);
        y.x += p.x; y.y += p.y; y.z += p.z; y.w += p.w;
    }

    float s  = y.x + y.y + y.z + y.w;
    float ss = y.x * y.x + y.y * y.y + y.z * y.z + y.w * y.w;
    #pragma unroll
    for (int m = 1; m < 32; m <<= 1) {
        s  += __shfl_xor(s, m);
        ss += __shfl_xor(ss, m);
    }
    const float mu  = s * (1.f / 128.f);
    const float var = ss * (1.f / 128.f) - mu * mu;
    const float rs  = rsqrtf(var + 1e-5f);

    float4 gg = *(const float4*)(gamma + c0);
    float4 be = *(const float4*)(beta + c0);
    float4 o4 = { (y.x - mu) * rs * gg.x + be.x, (y.y - mu) * rs * gg.y + be.y,
                  (y.z - mu) * rs * gg.z + be.z, (y.w - mu) * rs * gg.w + be.w };
    *(float4*)(out + off) = o4;
}

extern "C" void kernel_launch(void* const* d_in, const int* in_sizes, int n_in,
                              void* d_out, int out_size, void* d_ws, size_t ws_size,
                              hipStream_t stream) {
    const float* x     = (const float*)d_in[0];
    const float* sc    = (const float*)d_in[1];
    const float* tr    = (const float*)d_in[2];
    const float* lcw   = (const float*)d_in[3];
    const float* w1    = (const float*)d_in[4];
    const float* gamma = (const float*)d_in[5];
    const float* beta  = (const float*)d_in[6];
    float* out = (float*)d_out;

    char* ws = (char*)d_ws;
    f16*   WB    = (f16*)(ws + WB_OFF);
    f16*   xh    = (f16*)(ws + XH_OFF);
    float* bias  = (float*)(ws + BIAS_OFF);
    float* parts = (float*)(ws + PARTS_OFF);

    const size_t need8 = PARTS_OFF + 8ull * NB * OUT * 4ull;   // ~39.9 MB

    prep_kernel<<<1545, 256, 0, stream>>>(x, lcw, w1, sc, tr, WB, xh, bias);
    if (ws_size >= need8) {
        lc_gemm<8><<<512, 512, 0, stream>>>(xh, WB, parts);
        reduce_ln<8><<<1024, 256, 0, stream>>>(parts, bias, gamma, beta, out);
    } else {
        lc_gemm<4><<<256, 512, 0, stream>>>(xh, WB, parts);
        reduce_ln<4><<<1024, 256, 0, stream>>>(parts, bias, gamma, beta, out);
    }
}

// Round 8
// 132.004 us; speedup vs baseline: 1.0574x; 1.0574x over previous
//
#include <hip/hip_runtime.h>
#include <hip/hip_bf16.h>

typedef _Float16 f16;
typedef __attribute__((ext_vector_type(8))) _Float16 f16x8;
typedef __attribute__((ext_vector_type(4))) float f32x4;

#define IN 128
#define OUT 128
#define NB 8192
#define KSPLIT 4
#define CPK 32

// ws layout (bytes)
#define WB_OFF   0ull
#define XH_OFF   4227072ull          // 129*128*128*2
#define BIAS_OFF 6324224ull          // + 8192*128*2
#define PARTS_OFF 6324736ull         // + 512

// ---- prep: WB f16 [129][o][j] (c<128: lc_w[o,pos(c,j)], diag 0; c=128: w1*scale),
// ---- xh f16 = (x - tr)/sc, bias[o] = sum_j tr[j]*w1[o,j]
__global__ __launch_bounds__(256) void prep_kernel(
    const float* __restrict__ x, const float* __restrict__ lcw, const float* __restrict__ w1,
    const float* __restrict__ sc, const float* __restrict__ tr,
    f16* __restrict__ WB, f16* __restrict__ xh, float* __restrict__ bias)
{
    const int bid = blockIdx.x;
    if (bid < 1032) {                          // WB: 129*16384 f16 elems
        size_t idx = (size_t)bid * 2048 + (size_t)threadIdx.x * 8;
        int c   = (int)(idx >> 14);
        int rem = (int)(idx & 16383);
        int o   = rem >> 7;
        int j0  = rem & 127;
        f16x8 v;
        if (c < 128) {
            const float* lr = lcw + (size_t)o * 16256 + (size_t)c * 127;
            #pragma unroll
            for (int e = 0; e < 8; ++e) {
                int j = j0 + e;
                float f = (j == c) ? 0.f : lr[(j < c) ? j : (j - 1)];
                v[e] = (f16)f;
            }
        } else {
            #pragma unroll
            for (int e = 0; e < 8; ++e) {
                int j = j0 + e;
                v[e] = (f16)(w1[o * 128 + j] * sc[j]);
            }
        }
        *(f16x8*)(WB + idx) = v;
    } else if (bid < 1544) {                   // xh
        size_t idx = (size_t)(bid - 1032) * 2048 + (size_t)threadIdx.x * 8;
        int j0 = (int)(idx & 127);
        const float4 x0 = *(const float4*)(x + idx);
        const float4 x1 = *(const float4*)(x + idx + 4);
        const float4 s0 = *(const float4*)(sc + j0);
        const float4 s1 = *(const float4*)(sc + j0 + 4);
        const float4 t0 = *(const float4*)(tr + j0);
        const float4 t1 = *(const float4*)(tr + j0 + 4);
        f16x8 v;
        v[0] = (f16)((x0.x - t0.x) / s0.x); v[1] = (f16)((x0.y - t0.y) / s0.y);
        v[2] = (f16)((x0.z - t0.z) / s0.z); v[3] = (f16)((x0.w - t0.w) / s0.w);
        v[4] = (f16)((x1.x - t1.x) / s1.x); v[5] = (f16)((x1.y - t1.y) / s1.y);
        v[6] = (f16)((x1.z - t1.z) / s1.z); v[7] = (f16)((x1.w - t1.w) / s1.w);
        *(f16x8*)(xh + idx) = v;
    } else {                                   // bias
        const int lane = threadIdx.x & 63;
        const int wv   = threadIdx.x >> 6;
        const float2 t2 = *(const float2*)(tr + lane * 2);
        for (int o = wv; o < 128; o += 4) {
            const float2 w2 = *(const float2*)(w1 + o * 128 + lane * 2);
            float s = t2.x * w2.x + t2.y * w2.y;
            #pragma unroll
            for (int m = 1; m < 64; m <<= 1) s += __shfl_xor(s, m);
            if (lane == 0) bias[o] = s;
        }
    }
}

// ---- main: 256 WGs (64 M-tiles x 4 K-splits), 512 thr = 8 waves (2M x 4N), 1 block/CU.
// 3-buffer LDS ring, ONE barrier per chunk, counted vmcnt(4) (vmcnt(0) only on last),
// stage issued before compute (T14), setprio around MFMA cluster (T5).
__global__ __launch_bounds__(512, 1) void lc_gemm(
    const f16* __restrict__ xh, const f16* __restrict__ WB, float* __restrict__ parts)
{
    __shared__ f16 Bb[3][16384];               // 96 KB ring
    __shared__ f16 xls[(CPK + 1) * 128];       // 8448 B x-column slice

    const int tid = threadIdx.x;
    const int bid = blockIdx.x;
    const int mt  = bid >> 2;
    const int kq  = bid & 3;
    const int row0 = mt << 7;

    const int lane = tid & 63;
    const int wv   = tid >> 6;
    const int wm   = wv >> 2;                  // 0..1 : 64-row half
    const int wn   = wv & 3;                   // 0..3 : 32-col group
    const int cl   = lane & 15;
    const int kg   = lane >> 4;

    const int c_lo = (kq == 0) ? 0 : (1 + kq * CPK);
    const int nc   = (kq == 0) ? (CPK + 1) : CPK;

    // ---- A-base fragments, resident whole kernel
    f16x8 ab[4][4];
    #pragma unroll
    for (int rb = 0; rb < 4; ++rb) {
        const size_t rw = (size_t)(row0 + wm * 64 + rb * 16 + cl) * IN;
        #pragma unroll
        for (int s = 0; s < 4; ++s)
            ab[rb][s] = *(const f16x8*)(xh + rw + s * 32 + kg * 8);
    }
    #pragma unroll
    for (int rb = 0; rb < 4; ++rb)
        #pragma unroll
        for (int s = 0; s < 4; ++s)
            asm volatile("" : "+v"(ab[rb][s]));      // pin: no remat/sink

    // ---- DMA source offsets (pre-swizzled: bits4-7 ^= o&15) + LDS read offsets
    int dmac[4];
    #pragma unroll
    for (int p = 0; p < 4; ++p) {
        int L = ((p * 8 + wv) << 10) | (lane << 4);
        dmac[p] = L ^ (((L >> 8) & 15) << 4);
    }
    int boff[2][4];
    #pragma unroll
    for (int cb = 0; cb < 2; ++cb)
        #pragma unroll
        for (int s = 0; s < 4; ++s) {
            int o = wn * 32 + cb * 16 + cl;
            boff[cb][s] = (o << 8) + ((((s << 2) + kg) ^ (o & 15)) << 4);
        }

    auto stageB = [&](int c, int buf) {
        const char* src = (const char*)WB + ((size_t)c << 15);
        #pragma unroll
        for (int p = 0; p < 4; ++p) {
            __builtin_amdgcn_global_load_lds(
                (const __attribute__((address_space(1))) unsigned int*)(src + dmac[p]),
                (__attribute__((address_space(3))) unsigned int*)((char*)(&Bb[buf][0]) + ((p * 8 + wv) << 10)),
                16, 0, 0);
        }
    };

    f32x4 acc[4][2];
    #pragma unroll
    for (int rb = 0; rb < 4; ++rb)
        #pragma unroll
        for (int cb = 0; cb < 2; ++cb)
            acc[rb][cb] = (f32x4){0.f, 0.f, 0.f, 0.f};

    // ---- prologue: xls fill + stage chunks 0,1 ; full drain once
    for (int cp = tid >> 7; cp < nc; cp += 4) {
        int c = c_lo + cp;
        xls[cp * 128 + (tid & 127)] =
            (c < 128) ? xh[(size_t)(row0 + (tid & 127)) * IN + c] : (f16)1.0f;
    }
    stageB(c_lo + 0, 0);
    stageB(c_lo + 1, 1);
    __syncthreads();

#define KLOOP(NCV)                                                              \
    {                                                                           \
        constexpr int NC = NCV;                                                 \
        _Pragma("unroll")                                                       \
        for (int t = 0; t < NC; ++t) {                                          \
            if (t >= 1) {                                                       \
                if (t + 1 < NC) asm volatile("s_waitcnt vmcnt(4)" ::: "memory");\
                else            asm volatile("s_waitcnt vmcnt(0)" ::: "memory");\
                __builtin_amdgcn_s_barrier();                                   \
                __builtin_amdgcn_sched_barrier(0);                              \
            }                                                                   \
            if (t + 2 < NC) stageB(c_lo + t + 2, (t + 2) % 3);                  \
            const char* bbase = (const char*)(&Bb[t % 3][0]);                   \
            f16x8 bf[2][4];                                                     \
            _Pragma("unroll")                                                   \
            for (int cb = 0; cb < 2; ++cb)                                      \
                _Pragma("unroll")                                               \
                for (int s = 0; s < 4; ++s)                                     \
                    bf[cb][s] = *(const f16x8*)(bbase + boff[cb][s]);           \
            f16 xs[4];                                                          \
            _Pragma("unroll")                                                   \
            for (int rb = 0; rb < 4; ++rb)                                      \
                xs[rb] = xls[t * 128 + wm * 64 + rb * 16 + cl];                 \
            __builtin_amdgcn_s_setprio(1);                                      \
            _Pragma("unroll")                                                   \
            for (int s = 0; s < 4; ++s)                                         \
                _Pragma("unroll")                                               \
                for (int rb = 0; rb < 4; ++rb) {                                \
                    f16x8 xbv;                                                  \
                    _Pragma("unroll")                                           \
                    for (int e = 0; e < 8; ++e) xbv[e] = xs[rb];                \
                    f16x8 af = ab[rb][s] * xbv;                                 \
                    _Pragma("unroll")                                           \
                    for (int cb = 0; cb < 2; ++cb)                              \
                        acc[rb][cb] = __builtin_amdgcn_mfma_f32_16x16x32_f16(   \
                            af, bf[cb][s], acc[rb][cb], 0, 0, 0);               \
                }                                                               \
            __builtin_amdgcn_s_setprio(0);                                      \
        }                                                                       \
    }

    if (kq == 0) KLOOP(CPK + 1) else KLOOP(CPK)
#undef KLOOP

    float* po = parts + (size_t)kq * ((size_t)NB * OUT);
    #pragma unroll
    for (int rb = 0; rb < 4; ++rb) {
        const int grow = row0 + wm * 64 + rb * 16 + kg * 4;
        #pragma unroll
        for (int cb = 0; cb < 2; ++cb) {
            const int col = wn * 32 + cb * 16 + cl;
            #pragma unroll
            for (int q = 0; q < 4; ++q)
                po[(size_t)(grow + q) * OUT + col] = acc[rb][cb][q];
        }
    }
}

// ---- reduce split-K partials + bias, then LayerNorm. 32 lanes per row (float4/lane).
__global__ __launch_bounds__(256) void reduce_ln(
    const float* __restrict__ parts, const float* __restrict__ bias,
    const float* __restrict__ gamma, const float* __restrict__ beta,
    float* __restrict__ out)
{
    const int lane = threadIdx.x & 63;
    const int l5   = lane & 31;
    const int row  = blockIdx.x * 8 + (threadIdx.x >> 6) * 2 + (lane >> 5);
    const int c0   = l5 * 4;
    const size_t off = (size_t)row * OUT + c0;
    const size_t Q = (size_t)NB * OUT;

    float4 bb = *(const float4*)(bias + c0);
    float4 y = bb;
    #pragma unroll
    for (int k = 0; k < KSPLIT; ++k) {
        float4 p = *(const float4*)(parts + (size_t)k * Q + off);
        y.x += p.x; y.y += p.y; y.z += p.z; y.w += p.w;
    }

    float s  = y.x + y.y + y.z + y.w;
    float ss = y.x * y.x + y.y * y.y + y.z * y.z + y.w * y.w;
    #pragma unroll
    for (int m = 1; m < 32; m <<= 1) {
        s  += __shfl_xor(s, m);
        ss += __shfl_xor(ss, m);
    }
    const float mu  = s * (1.f / 128.f);
    const float var = ss * (1.f / 128.f) - mu * mu;
    const float rs  = rsqrtf(var + 1e-5f);

    float4 gg = *(const float4*)(gamma + c0);
    float4 be = *(const float4*)(beta + c0);
    float4 o4 = { (y.x - mu) * rs * gg.x + be.x, (y.y - mu) * rs * gg.y + be.y,
                  (y.z - mu) * rs * gg.z + be.z, (y.w - mu) * rs * gg.w + be.w };
    *(float4*)(out + off) = o4;
}

extern "C" void kernel_launch(void* const* d_in, const int* in_sizes, int n_in,
                              void* d_out, int out_size, void* d_ws, size_t ws_size,
                              hipStream_t stream) {
    const float* x     = (const float*)d_in[0];
    const float* sc    = (const float*)d_in[1];
    const float* tr    = (const float*)d_in[2];
    const float* lcw   = (const float*)d_in[3];
    const float* w1    = (const float*)d_in[4];
    const float* gamma = (const float*)d_in[5];
    const float* beta  = (const float*)d_in[6];
    float* out = (float*)d_out;

    char* ws = (char*)d_ws;
    f16*   WB    = (f16*)(ws + WB_OFF);
    f16*   xh    = (f16*)(ws + XH_OFF);
    float* bias  = (float*)(ws + BIAS_OFF);
    float* parts = (float*)(ws + PARTS_OFF);

    prep_kernel<<<1545, 256, 0, stream>>>(x, lcw, w1, sc, tr, WB, xh, bias);
    lc_gemm<<<256, 512, 0, stream>>>(xh, WB, parts);
    reduce_ln<<<1024, 256, 0, stream>>>(parts, bias, gamma, beta, out);
}

// Round 9
// 129.865 us; speedup vs baseline: 1.0748x; 1.0165x over previous
//
#include <hip/hip_runtime.h>
#include <hip/hip_bf16.h>

typedef _Float16 f16;
typedef __attribute__((ext_vector_type(8))) _Float16 f16x8;
typedef __attribute__((ext_vector_type(4))) float f32x4;

#define IN 128
#define OUT 128
#define NB 8192
#define KSPLIT 4
#define CPK 32

// ws layout (bytes)
#define WB_OFF   0ull
#define XH_OFF   4227072ull          // 129*128*128*2
#define BIAS_OFF 6324224ull          // + 8192*128*2
#define PARTS_OFF 6324736ull         // + 512

// ---- prep: WB f16 [129][o][j] (c<128: lc_w[o,pos(c,j)], diag 0; c=128: w1*scale),
// ---- xh f16 = (x - tr)/sc, bias[o] = sum_j tr[j]*w1[o,j]
__global__ __launch_bounds__(256) void prep_kernel(
    const float* __restrict__ x, const float* __restrict__ lcw, const float* __restrict__ w1,
    const float* __restrict__ sc, const float* __restrict__ tr,
    f16* __restrict__ WB, f16* __restrict__ xh, float* __restrict__ bias)
{
    const int bid = blockIdx.x;
    if (bid < 1032) {                          // WB: 129*16384 f16 elems
        size_t idx = (size_t)bid * 2048 + (size_t)threadIdx.x * 8;
        int c   = (int)(idx >> 14);
        int rem = (int)(idx & 16383);
        int o   = rem >> 7;
        int j0  = rem & 127;
        f16x8 v;
        if (c < 128) {
            const float* lr = lcw + (size_t)o * 16256 + (size_t)c * 127;
            #pragma unroll
            for (int e = 0; e < 8; ++e) {
                int j = j0 + e;
                float f = (j == c) ? 0.f : lr[(j < c) ? j : (j - 1)];
                v[e] = (f16)f;
            }
        } else {
            #pragma unroll
            for (int e = 0; e < 8; ++e) {
                int j = j0 + e;
                v[e] = (f16)(w1[o * 128 + j] * sc[j]);
            }
        }
        *(f16x8*)(WB + idx) = v;
    } else if (bid < 1544) {                   // xh
        size_t idx = (size_t)(bid - 1032) * 2048 + (size_t)threadIdx.x * 8;
        int j0 = (int)(idx & 127);
        const float4 x0 = *(const float4*)(x + idx);
        const float4 x1 = *(const float4*)(x + idx + 4);
        const float4 s0 = *(const float4*)(sc + j0);
        const float4 s1 = *(const float4*)(sc + j0 + 4);
        const float4 t0 = *(const float4*)(tr + j0);
        const float4 t1 = *(const float4*)(tr + j0 + 4);
        f16x8 v;
        v[0] = (f16)((x0.x - t0.x) / s0.x); v[1] = (f16)((x0.y - t0.y) / s0.y);
        v[2] = (f16)((x0.z - t0.z) / s0.z); v[3] = (f16)((x0.w - t0.w) / s0.w);
        v[4] = (f16)((x1.x - t1.x) / s1.x); v[5] = (f16)((x1.y - t1.y) / s1.y);
        v[6] = (f16)((x1.z - t1.z) / s1.z); v[7] = (f16)((x1.w - t1.w) / s1.w);
        *(f16x8*)(xh + idx) = v;
    } else {                                   // bias
        const int lane = threadIdx.x & 63;
        const int wv   = threadIdx.x >> 6;
        const float2 t2 = *(const float2*)(tr + lane * 2);
        for (int o = wv; o < 128; o += 4) {
            const float2 w2 = *(const float2*)(w1 + o * 128 + lane * 2);
            float s = t2.x * w2.x + t2.y * w2.y;
            #pragma unroll
            for (int m = 1; m < 64; m <<= 1) s += __shfl_xor(s, m);
            if (lane == 0) bias[o] = s;
        }
    }
}

// ---- main: 256 WGs (64 M-tiles x 4 K-splits), 512 thr = 8 waves (2M x 4N), 1 block/CU.
// 2 sub-phases per chunk (m201 pattern): each = {4 ds_read_b128 + 2 stage-issues ->
// sched_barrier -> setprio(1) + 16 MFMA + setprio(0)}, mid-chunk s_barrier,
// counted vmcnt(4) once per chunk (vmcnt(0) only last), 3-buffer LDS ring.
__global__ __launch_bounds__(512, 1) void lc_gemm(
    const f16* __restrict__ xh, const f16* __restrict__ WB, float* __restrict__ parts)
{
    __shared__ f16 Bb[3][16384];               // 96 KB ring
    __shared__ f16 xls[(CPK + 1) * 128];       // 8448 B x-column slice

    const int tid = threadIdx.x;
    const int bid = blockIdx.x;
    const int mt  = bid >> 2;
    const int kq  = bid & 3;
    const int row0 = mt << 7;

    const int lane = tid & 63;
    const int wv   = tid >> 6;
    const int wm   = wv >> 2;                  // 0..1 : 64-row half
    const int wn   = wv & 3;                   // 0..3 : 32-col group
    const int cl   = lane & 15;
    const int kg   = lane >> 4;

    const int c_lo = (kq == 0) ? 0 : (1 + kq * CPK);
    const int nc   = (kq == 0) ? (CPK + 1) : CPK;

    // ---- A-base fragments, resident whole kernel
    f16x8 ab[4][4];
    #pragma unroll
    for (int rb = 0; rb < 4; ++rb) {
        const size_t rw = (size_t)(row0 + wm * 64 + rb * 16 + cl) * IN;
        #pragma unroll
        for (int s = 0; s < 4; ++s)
            ab[rb][s] = *(const f16x8*)(xh + rw + s * 32 + kg * 8);
    }
    #pragma unroll
    for (int rb = 0; rb < 4; ++rb)
        #pragma unroll
        for (int s = 0; s < 4; ++s)
            asm volatile("" : "+v"(ab[rb][s]));      // pin: no remat/sink

    // ---- DMA source offsets (pre-swizzled: bits4-7 ^= o&15) + LDS read offsets
    int dmac[4];
    #pragma unroll
    for (int p = 0; p < 4; ++p) {
        int L = ((p * 8 + wv) << 10) | (lane << 4);
        dmac[p] = L ^ (((L >> 8) & 15) << 4);
    }
    int boff[2][4];
    #pragma unroll
    for (int cb = 0; cb < 2; ++cb)
        #pragma unroll
        for (int s = 0; s < 4; ++s) {
            int o = wn * 32 + cb * 16 + cl;
            boff[cb][s] = (o << 8) + ((((s << 2) + kg) ^ (o & 15)) << 4);
        }

    auto stageHalf = [&](int c, int buf, int h) {
        const char* src = (const char*)WB + ((size_t)c << 15);
        #pragma unroll
        for (int p = h * 2; p < h * 2 + 2; ++p) {
            __builtin_amdgcn_global_load_lds(
                (const __attribute__((address_space(1))) unsigned int*)(src + dmac[p]),
                (__attribute__((address_space(3))) unsigned int*)((char*)(&Bb[buf][0]) + ((p * 8 + wv) << 10)),
                16, 0, 0);
        }
    };

    f32x4 acc[4][2];
    #pragma unroll
    for (int rb = 0; rb < 4; ++rb)
        #pragma unroll
        for (int cb = 0; cb < 2; ++cb)
            acc[rb][cb] = (f32x4){0.f, 0.f, 0.f, 0.f};

    // ---- prologue: xls fill + stage chunks 0,1 ; full drain once
    for (int cp = tid >> 7; cp < nc; cp += 4) {
        int c = c_lo + cp;
        xls[cp * 128 + (tid & 127)] =
            (c < 128) ? xh[(size_t)(row0 + (tid & 127)) * IN + c] : (f16)1.0f;
    }
    stageHalf(c_lo + 0, 0, 0); stageHalf(c_lo + 0, 0, 1);
    stageHalf(c_lo + 1, 1, 0); stageHalf(c_lo + 1, 1, 1);
    __syncthreads();

#define KLOOP(NCV)                                                              \
    {                                                                           \
        constexpr int NC = NCV;                                                 \
        _Pragma("unroll")                                                       \
        for (int t = 0; t < NC; ++t) {                                          \
            if (t >= 1) {                                                       \
                if (t + 1 < NC) asm volatile("s_waitcnt vmcnt(4)" ::: "memory");\
                else            asm volatile("s_waitcnt vmcnt(0)" ::: "memory");\
                __builtin_amdgcn_s_barrier();                                   \
                __builtin_amdgcn_sched_barrier(0);                              \
            }                                                                   \
            const char* bbase = (const char*)(&Bb[t % 3][0]);                   \
            /* ---- phase A: K-low (s=0,1) ---- */                              \
            f16x8 bf0[2][2];                                                    \
            _Pragma("unroll")                                                   \
            for (int cb = 0; cb < 2; ++cb)                                      \
                _Pragma("unroll")                                               \
                for (int s = 0; s < 2; ++s)                                     \
                    bf0[cb][s] = *(const f16x8*)(bbase + boff[cb][s]);          \
            f16x8 xsp[4];                                                       \
            _Pragma("unroll")                                                   \
            for (int rb = 0; rb < 4; ++rb) {                                    \
                f16 xv = xls[t * 128 + wm * 64 + rb * 16 + cl];                 \
                _Pragma("unroll")                                               \
                for (int e = 0; e < 8; ++e) xsp[rb][e] = xv;                    \
            }                                                                   \
            if (t + 2 < NC) stageHalf(c_lo + t + 2, (t + 2) % 3, 0);            \
            __builtin_amdgcn_sched_barrier(0);                                  \
            __builtin_amdgcn_s_setprio(1);                                      \
            _Pragma("unroll")                                                   \
            for (int s = 0; s < 2; ++s)                                         \
                _Pragma("unroll")                                               \
                for (int rb = 0; rb < 4; ++rb) {                                \
                    f16x8 af = ab[rb][s] * xsp[rb];                             \
                    _Pragma("unroll")                                           \
                    for (int cb = 0; cb < 2; ++cb)                              \
                        acc[rb][cb] = __builtin_amdgcn_mfma_f32_16x16x32_f16(   \
                            af, bf0[cb][s], acc[rb][cb], 0, 0, 0);              \
                }                                                               \
            __builtin_amdgcn_s_setprio(0);                                      \
            __builtin_amdgcn_sched_barrier(0);                                  \
            __builtin_amdgcn_s_barrier();                                       \
            /* ---- phase B: K-high (s=2,3) ---- */                             \
            f16x8 bf1[2][2];                                                    \
            _Pragma("unroll")                                                   \
            for (int cb = 0; cb < 2; ++cb)                                      \
                _Pragma("unroll")                                               \
                for (int s = 0; s < 2; ++s)                                     \
                    bf1[cb][s] = *(const f16x8*)(bbase + boff[cb][s + 2]);      \
            if (t + 2 < NC) stageHalf(c_lo + t + 2, (t + 2) % 3, 1);            \
            __builtin_amdgcn_sched_barrier(0);                                  \
            __builtin_amdgcn_s_setprio(1);                                      \
            _Pragma("unroll")                                                   \
            for (int s = 0; s < 2; ++s)                                         \
                _Pragma("unroll")                                               \
                for (int rb = 0; rb < 4; ++rb) {                                \
                    f16x8 af = ab[rb][s + 2] * xsp[rb];                         \
                    _Pragma("unroll")                                           \
                    for (int cb = 0; cb < 2; ++cb)                              \
                        acc[rb][cb] = __builtin_amdgcn_mfma_f32_16x16x32_f16(   \
                            af, bf1[cb][s], acc[rb][cb], 0, 0, 0);              \
                }                                                               \
            __builtin_amdgcn_s_setprio(0);                                      \
            __builtin_amdgcn_sched_barrier(0);                                  \
        }                                                                       \
    }

    if (kq == 0) KLOOP(CPK + 1) else KLOOP(CPK)
#undef KLOOP

    float* po = parts + (size_t)kq * ((size_t)NB * OUT);
    #pragma unroll
    for (int rb = 0; rb < 4; ++rb) {
        const int grow = row0 + wm * 64 + rb * 16 + kg * 4;
        #pragma unroll
        for (int cb = 0; cb < 2; ++cb) {
            const int col = wn * 32 + cb * 16 + cl;
            #pragma unroll
            for (int q = 0; q < 4; ++q)
                po[(size_t)(grow + q) * OUT + col] = acc[rb][cb][q];
        }
    }
}

// ---- reduce split-K partials + bias, then LayerNorm. 32 lanes per row (float4/lane).
__global__ __launch_bounds__(256) void reduce_ln(
    const float* __restrict__ parts, const float* __restrict__ bias,
    const float* __restrict__ gamma, const float* __restrict__ beta,
    float* __restrict__ out)
{
    const int lane = threadIdx.x & 63;
    const int l5   = lane & 31;
    const int row  = blockIdx.x * 8 + (threadIdx.x >> 6) * 2 + (lane >> 5);
    const int c0   = l5 * 4;
    const size_t off = (size_t)row * OUT + c0;
    const size_t Q = (size_t)NB * OUT;

    float4 bb = *(const float4*)(bias + c0);
    float4 y = bb;
    #pragma unroll
    for (int k = 0; k < KSPLIT; ++k) {
        float4 p = *(const float4*)(parts + (size_t)k * Q + off);
        y.x += p.x; y.y += p.y; y.z += p.z; y.w += p.w;
    }

    float s  = y.x + y.y + y.z + y.w;
    float ss = y.x * y.x + y.y * y.y + y.z * y.z + y.w * y.w;
    #pragma unroll
    for (int m = 1; m < 32; m <<= 1) {
        s  += __shfl_xor(s, m);
        ss += __shfl_xor(ss, m);
    }
    const float mu  = s * (1.f / 128.f);
    const float var = ss * (1.f / 128.f) - mu * mu;
    const float rs  = rsqrtf(var + 1e-5f);

    float4 gg = *(const float4*)(gamma + c0);
    float4 be = *(const float4*)(beta + c0);
    float4 o4 = { (y.x - mu) * rs * gg.x + be.x, (y.y - mu) * rs * gg.y + be.y,
                  (y.z - mu) * rs * gg.z + be.z, (y.w - mu) * rs * gg.w + be.w };
    *(float4*)(out + off) = o4;
}

extern "C" void kernel_launch(void* const* d_in, const int* in_sizes, int n_in,
                              void* d_out, int out_size, void* d_ws, size_t ws_size,
                              hipStream_t stream) {
    const float* x     = (const float*)d_in[0];
    const float* sc    = (const float*)d_in[1];
    const float* tr    = (const float*)d_in[2];
    const float* lcw   = (const float*)d_in[3];
    const float* w1    = (const float*)d_in[4];
    const float* gamma = (const float*)d_in[5];
    const float* beta  = (const float*)d_in[6];
    float* out = (float*)d_out;

    char* ws = (char*)d_ws;
    f16*   WB    = (f16*)(ws + WB_OFF);
    f16*   xh    = (f16*)(ws + XH_OFF);
    float* bias  = (float*)(ws + BIAS_OFF);
    float* parts = (float*)(ws + PARTS_OFF);

    prep_kernel<<<1545, 256, 0, stream>>>(x, lcw, w1, sc, tr, WB, xh, bias);
    lc_gemm<<<256, 512, 0, stream>>>(xh, WB, parts);
    reduce_ln<<<1024, 256, 0, stream>>>(parts, bias, gamma, beta, out);
}